// Round 1
// baseline (379.394 us; speedup 1.0000x reference)
//
#include <hip/hip_runtime.h>
#include <hip/hip_bf16.h>

#define D_MODEL 1024
#define N_HEADS 16
#define DK 64
#define SEQ 2048
#define BATCH 4

typedef __attribute__((ext_vector_type(4))) float   f32v4;
typedef __attribute__((ext_vector_type(8))) __bf16  bf16x8;
typedef __attribute__((ext_vector_type(8))) unsigned short u16v8;
typedef __attribute__((ext_vector_type(4))) unsigned short u16v4;

__device__ __forceinline__ int swz(int byte) {
    // XOR-swizzle for 128-byte-row LDS tiles: spread 16B slots across banks
    return byte ^ (((byte >> 7) & 7) << 4);
}

__device__ __forceinline__ unsigned short bfb(float f) {
    return __builtin_bit_cast(unsigned short, (__bf16)f);
}
__device__ __forceinline__ float bff(unsigned short u) {
    return (float)__builtin_bit_cast(__bf16, u);
}

__device__ __forceinline__ f32v4 mfma16(bf16x8 a, bf16x8 b, f32v4 c) {
    return __builtin_amdgcn_mfma_f32_16x16x32_bf16(a, b, c, 0, 0, 0);
}

// ---------------------------------------------------------------------------
// Transpose+convert the four 1024x1024 fp32 weight matrices to bf16 Wt[n][k]
// ---------------------------------------------------------------------------
__global__ __launch_bounds__(256) void wtrans_kernel(const float* wq, const float* wk,
                                                     const float* wv, const float* wo,
                                                     unsigned short* wt) {
    __shared__ unsigned short ts[64][65];
    int bid = blockIdx.x;
    int mat = bid >> 8;            // 0..3
    int tile = bid & 255;          // 16x16 tiles of 64x64
    int kb = (tile >> 4) * 64;
    int nb = (tile & 15) * 64;
    const float* W = (mat == 0) ? wq : (mat == 1) ? wk : (mat == 2) ? wv : wo;
    unsigned short* out = wt + (size_t)mat * D_MODEL * D_MODEL;
    int t = threadIdx.x;
#pragma unroll
    for (int p = 0; p < 4; ++p) {
        int row = p * 16 + (t >> 4);
        int c0 = (t & 15) * 4;
        f32v4 v = *(const f32v4*)(W + (size_t)(kb + row) * D_MODEL + nb + c0);
#pragma unroll
        for (int j = 0; j < 4; ++j) ts[row][c0 + j] = bfb(v[j]);
    }
    __syncthreads();
#pragma unroll
    for (int p = 0; p < 2; ++p) {
        int n = p * 32 + (t >> 3);
        int k0 = (t & 7) * 8;
        u16v8 o;
#pragma unroll
        for (int j = 0; j < 8; ++j) o[j] = ts[k0 + j][n];
        *(u16v8*)(out + (size_t)(nb + n) * D_MODEL + kb + k0) = o;
    }
}

// ---------------------------------------------------------------------------
// GEMM: C[8192x1024] = A[8192x1024] * W[1024x1024] + bias
// ABF16: 0 = A fp32 (converted on the fly), 1 = A bf16
// OMODE: 0 = bf16 output in split-head [B,H,S,DK] layout, 1 = fp32 linear
// ---------------------------------------------------------------------------
template<int ABF16, int OMODE>
__global__ __launch_bounds__(256) void gemm_kernel(const void* Aptr, const unsigned short* Wt,
                                                   const float* bias, void* Cptr) {
    __shared__ unsigned short lds_a[128 * 64];   // rows 128B, swizzled
    __shared__ unsigned short lds_b[128 * 64];
    int bid = blockIdx.x;
    int nb = (bid & 7) * 128;
    int mb = (bid >> 3) * 128;
    int tid = threadIdx.x;
    int lane = tid & 63, wid = tid >> 6;
    int l15 = lane & 15, g = lane >> 4;
    int wm = (wid >> 1) * 64, wn = (wid & 1) * 64;

    f32v4 acc[4][4] = {};

    for (int kt = 0; kt < D_MODEL / 64; ++kt) {
        int k0 = kt * 64;
        __syncthreads();
        if constexpr (ABF16) {
            const unsigned short* A = (const unsigned short*)Aptr;
#pragma unroll
            for (int p = 0; p < 4; ++p) {
                int row = p * 32 + (tid >> 3);
                int c0 = (tid & 7) * 8;
                u16v8 v = *(const u16v8*)(A + (size_t)(mb + row) * D_MODEL + k0 + c0);
                *(u16v8*)((char*)lds_a + swz(row * 128 + c0 * 2)) = v;
            }
        } else {
            const float* A = (const float*)Aptr;
#pragma unroll
            for (int p = 0; p < 8; ++p) {
                int row = p * 16 + (tid >> 4);
                int c0 = (tid & 15) * 4;
                f32v4 v = *(const f32v4*)(A + (size_t)(mb + row) * D_MODEL + k0 + c0);
                u16v4 o;
#pragma unroll
                for (int j = 0; j < 4; ++j) o[j] = bfb(v[j]);
                *(u16v4*)((char*)lds_a + swz(row * 128 + c0 * 2)) = o;
            }
        }
#pragma unroll
        for (int p = 0; p < 4; ++p) {
            int row = p * 32 + (tid >> 3);
            int c0 = (tid & 7) * 8;
            u16v8 v = *(const u16v8*)(Wt + (size_t)(nb + row) * D_MODEL + k0 + c0);
            *(u16v8*)((char*)lds_b + swz(row * 128 + c0 * 2)) = v;
        }
        __syncthreads();
#pragma unroll
        for (int kk = 0; kk < 2; ++kk) {
            bf16x8 af[4], bfr[4];
#pragma unroll
            for (int mt = 0; mt < 4; ++mt)
                af[mt] = *(bf16x8*)((char*)lds_a + swz((wm + mt * 16 + l15) * 128 + kk * 64 + g * 16));
#pragma unroll
            for (int nt = 0; nt < 4; ++nt)
                bfr[nt] = *(bf16x8*)((char*)lds_b + swz((wn + nt * 16 + l15) * 128 + kk * 64 + g * 16));
#pragma unroll
            for (int mt = 0; mt < 4; ++mt)
#pragma unroll
                for (int nt = 0; nt < 4; ++nt)
                    acc[mt][nt] = mfma16(af[mt], bfr[nt], acc[mt][nt]);
        }
    }
    // epilogue: C[row=4g+r][col=l15] per 16x16 tile
#pragma unroll
    for (int nt = 0; nt < 4; ++nt) {
        int n = nb + wn + nt * 16 + l15;
        float bv = bias[n];
#pragma unroll
        for (int mt = 0; mt < 4; ++mt) {
#pragma unroll
            for (int r = 0; r < 4; ++r) {
                int m = mb + wm + mt * 16 + 4 * g + r;
                float val = acc[mt][nt][r] + bv;
                if constexpr (OMODE == 0) {
                    unsigned short* out = (unsigned short*)Cptr;
                    int bb = m >> 11, ss = m & 2047, hh = n >> 6, dd = n & 63;
                    out[(((size_t)(bb * N_HEADS + hh)) * SEQ + ss) * DK + dd] = bfb(val);
                } else {
                    float* out = (float*)Cptr;
                    out[(size_t)m * D_MODEL + n] = val;
                }
            }
        }
    }
}

// ---------------------------------------------------------------------------
// Transpose Vh [BH][S][DK] bf16 -> Vt [BH][DK][S] bf16
// ---------------------------------------------------------------------------
__global__ __launch_bounds__(256) void vtrans_kernel(const unsigned short* Vh, unsigned short* Vt) {
    __shared__ unsigned short ts[64][65];
    int bid = blockIdx.x;
    int bh = bid >> 5;
    int s0 = (bid & 31) * 64;
    int t = threadIdx.x;
    const unsigned short* in = Vh + (size_t)bh * SEQ * DK;
    unsigned short* out = Vt + (size_t)bh * DK * SEQ;
#pragma unroll
    for (int p = 0; p < 2; ++p) {
        int srow = p * 32 + (t >> 3);
        int d0 = (t & 7) * 8;
        u16v8 v = *(const u16v8*)(in + (size_t)(s0 + srow) * DK + d0);
#pragma unroll
        for (int j = 0; j < 8; ++j) ts[srow][d0 + j] = v[j];
    }
    __syncthreads();
#pragma unroll
    for (int p = 0; p < 2; ++p) {
        int d = p * 32 + (t >> 3);
        int sc0 = (t & 7) * 8;
        u16v8 o;
#pragma unroll
        for (int j = 0; j < 8; ++j) o[j] = ts[sc0 + j][d];
        *(u16v8*)(out + (size_t)d * SEQ + s0 + sc0) = o;
    }
}

// ---------------------------------------------------------------------------
// Causal flash attention. Block = 4 waves; wave w owns 16 q-rows.
// Qh,Kh: [BH][S][DK] bf16 ; Vt: [BH][DK][S] bf16 ; ctx out: [B][S][D_MODEL] bf16
// ---------------------------------------------------------------------------
__global__ __launch_bounds__(256) void attn_kernel(const unsigned short* Qh, const unsigned short* Kh,
                                                   const unsigned short* Vt, unsigned short* ctxp) {
    __shared__ unsigned short k_lds[64 * 64];
    __shared__ unsigned short v_lds[64 * 64];   // [d][key_local]
    __shared__ unsigned short p_lds[4][16 * 64];
    int bid = blockIdx.x;
    int qblk = bid & 31;
    int bh = bid >> 5;
    int bb = bh >> 4, hh = bh & 15;
    int tid = threadIdx.x;
    int wid = tid >> 6, lane = tid & 63;
    int l15 = lane & 15, g = lane >> 4;
    int qw0 = qblk * 64 + wid * 16;
    const unsigned short* Qb = Qh + (size_t)bh * SEQ * DK;
    const unsigned short* Kb = Kh + (size_t)bh * SEQ * DK;
    const unsigned short* Vb = Vt + (size_t)bh * DK * SEQ;

    // Q fragments, pre-scaled by 1/sqrt(dk)=0.125 (exact in bf16)
    bf16x8 qf[2];
#pragma unroll
    for (int kk = 0; kk < 2; ++kk) {
        u16v8 raw = *(const u16v8*)(Qb + (size_t)(qw0 + l15) * DK + kk * 32 + g * 8);
        u16v8 sc;
#pragma unroll
        for (int j = 0; j < 8; ++j) sc[j] = bfb(bff(raw[j]) * 0.125f);
        qf[kk] = __builtin_bit_cast(bf16x8, sc);
    }

    f32v4 acc[4] = {};
    float mrun[4], lrun[4];
#pragma unroll
    for (int r = 0; r < 4; ++r) { mrun[r] = -1e30f; lrun[r] = 0.f; }

    for (int kt = 0; kt <= qblk; ++kt) {
        __syncthreads();
#pragma unroll
        for (int p = 0; p < 2; ++p) {
            int row = p * 32 + (tid >> 3);
            int c0 = (tid & 7) * 8;
            u16v8 kv = *(const u16v8*)(Kb + (size_t)(kt * 64 + row) * DK + c0);
            *(u16v8*)((char*)k_lds + swz(row * 128 + c0 * 2)) = kv;
            u16v8 vv = *(const u16v8*)(Vb + (size_t)row * SEQ + kt * 64 + c0);
            *(u16v8*)((char*)v_lds + swz(row * 128 + c0 * 2)) = vv;
        }
        __syncthreads();

        f32v4 s[4] = {};
#pragma unroll
        for (int kk = 0; kk < 2; ++kk) {
#pragma unroll
            for (int c = 0; c < 4; ++c) {
                bf16x8 kf = *(bf16x8*)((char*)k_lds + swz((c * 16 + l15) * 128 + kk * 64 + g * 16));
                s[c] = mfma16(qf[kk], kf, s[c]);
            }
        }
        if (kt * 64 + 63 > qw0) {   // only the diagonal tile needs masking
#pragma unroll
            for (int c = 0; c < 4; ++c) {
                int key = kt * 64 + c * 16 + l15;
#pragma unroll
                for (int r = 0; r < 4; ++r) {
                    int qq = qw0 + 4 * g + r;
                    if (key > qq) s[c][r] = -1e30f;
                }
            }
        }
        // online softmax per owned row (rows 4g+r, key cols across 16 lanes)
#pragma unroll
        for (int r = 0; r < 4; ++r) {
            float mx = fmaxf(fmaxf(s[0][r], s[1][r]), fmaxf(s[2][r], s[3][r]));
#pragma unroll
            for (int off = 1; off < 16; off <<= 1) mx = fmaxf(mx, __shfl_xor(mx, off));
            float mn = fmaxf(mrun[r], mx);
            float co = __expf(mrun[r] - mn);
            mrun[r] = mn;
            float rs = 0.f;
#pragma unroll
            for (int c = 0; c < 4; ++c) {
                float pv = __expf(s[c][r] - mn);
                s[c][r] = pv;
                rs += pv;
            }
#pragma unroll
            for (int off = 1; off < 16; off <<= 1) rs += __shfl_xor(rs, off);
            lrun[r] = lrun[r] * co + rs;
#pragma unroll
            for (int c2 = 0; c2 < 4; ++c2) acc[c2][r] = acc[c2][r] * co;
        }
        // P (D-layout) -> per-wave LDS -> A-layout fragments
        unsigned short* pw = p_lds[wid];
#pragma unroll
        for (int c = 0; c < 4; ++c)
#pragma unroll
            for (int r = 0; r < 4; ++r)
                *(unsigned short*)((char*)pw + swz((4 * g + r) * 128 + (c * 16 + l15) * 2)) = bfb(s[c][r]);
#pragma unroll
        for (int kkp = 0; kkp < 2; ++kkp) {
            bf16x8 pa = *(bf16x8*)((char*)pw + swz(l15 * 128 + kkp * 64 + g * 16));
#pragma unroll
            for (int c2 = 0; c2 < 4; ++c2) {
                bf16x8 vf = *(bf16x8*)((char*)v_lds + swz((c2 * 16 + l15) * 128 + kkp * 64 + g * 16));
                acc[c2] = mfma16(pa, vf, acc[c2]);
            }
        }
    }
    // epilogue: ctx[b][s][h*64 + d] bf16
#pragma unroll
    for (int c2 = 0; c2 < 4; ++c2) {
#pragma unroll
        for (int r = 0; r < 4; ++r) {
            int qq = qw0 + 4 * g + r;
            float val = acc[c2][r] / lrun[r];
            ctxp[((size_t)(bb * SEQ + qq)) * D_MODEL + hh * DK + c2 * 16 + l15] = bfb(val);
        }
    }
}

// ---------------------------------------------------------------------------
extern "C" void kernel_launch(void* const* d_in, const int* in_sizes, int n_in,
                              void* d_out, int out_size, void* d_ws, size_t ws_size,
                              hipStream_t stream) {
    const float* q  = (const float*)d_in[0];
    const float* k  = (const float*)d_in[1];
    const float* v  = (const float*)d_in[2];
    // d_in[3] = mask (causal tril, known statically -> unused)
    const float* wq = (const float*)d_in[4];
    const float* bq = (const float*)d_in[5];
    const float* wk = (const float*)d_in[6];
    const float* bk = (const float*)d_in[7];
    const float* wv = (const float*)d_in[8];
    const float* bv = (const float*)d_in[9];
    const float* wo = (const float*)d_in[10];
    const float* bo = (const float*)d_in[11];

    // workspace layout (ushort elements): total 36M elems = 72 MB
    unsigned short* ws  = (unsigned short*)d_ws;
    const size_t M8 = (size_t)8 * 1024 * 1024;
    unsigned short* Qh  = ws;            // [BH][S][DK]
    unsigned short* Kh  = ws + M8;
    unsigned short* Vt  = ws + 2 * M8;   // [BH][DK][S]
    unsigned short* CTX = ws + 3 * M8;   // Vh temp, then attention output [B][S][D]
    unsigned short* WT  = ws + 4 * M8;   // 4 x [1024][1024] bf16 transposed weights
    const size_t MM = (size_t)D_MODEL * D_MODEL;

    wtrans_kernel<<<dim3(1024), dim3(256), 0, stream>>>(wq, wk, wv, wo, WT);
    gemm_kernel<0, 0><<<dim3(512), dim3(256), 0, stream>>>(q, WT + 0 * MM, bq, Qh);
    gemm_kernel<0, 0><<<dim3(512), dim3(256), 0, stream>>>(k, WT + 1 * MM, bk, Kh);
    gemm_kernel<0, 0><<<dim3(512), dim3(256), 0, stream>>>(v, WT + 2 * MM, bv, CTX); // Vh temp
    vtrans_kernel<<<dim3(2048), dim3(256), 0, stream>>>(CTX, Vt);
    attn_kernel<<<dim3(2048), dim3(256), 0, stream>>>(Qh, Kh, Vt, CTX);
    gemm_kernel<1, 1><<<dim3(512), dim3(256), 0, stream>>>(CTX, WT + 3 * MM, bo, (float*)d_out);
}

// Round 2
// 261.371 us; speedup vs baseline: 1.4516x; 1.4516x over previous
//
#include <hip/hip_runtime.h>
#include <hip/hip_bf16.h>

#define D_MODEL 1024
#define N_HEADS 16
#define DK 64
#define SEQ 2048
#define BATCH 4

typedef __attribute__((ext_vector_type(4))) float   f32v4;
typedef __attribute__((ext_vector_type(8))) __bf16  bf16x8;
typedef __attribute__((ext_vector_type(8))) unsigned short u16v8;
typedef __attribute__((ext_vector_type(4))) unsigned short u16v4;

__device__ __forceinline__ int swz(int byte) {
    return byte ^ (((byte >> 7) & 7) << 4);
}

__device__ __forceinline__ unsigned short bfb(float f) {
    return __builtin_bit_cast(unsigned short, (__bf16)f);
}
__device__ __forceinline__ float bff(unsigned short u) {
    return (float)__builtin_bit_cast(__bf16, u);
}

__device__ __forceinline__ f32v4 mfma16(bf16x8 a, bf16x8 b, f32v4 c) {
    return __builtin_amdgcn_mfma_f32_16x16x32_bf16(a, b, c, 0, 0, 0);
}

// ---------------------------------------------------------------------------
// Transpose+convert the four 1024x1024 fp32 weight matrices to bf16 Wt[n][k]
// ---------------------------------------------------------------------------
__global__ __launch_bounds__(256) void wtrans_kernel(const float* wq, const float* wk,
                                                     const float* wv, const float* wo,
                                                     unsigned short* wt) {
    __shared__ unsigned short ts[64][65];
    int bid = blockIdx.x;
    int mat = bid >> 8;            // 0..3
    int tile = bid & 255;          // 16x16 tiles of 64x64
    int kb = (tile >> 4) * 64;
    int nb = (tile & 15) * 64;
    const float* W = (mat == 0) ? wq : (mat == 1) ? wk : (mat == 2) ? wv : wo;
    unsigned short* out = wt + (size_t)mat * D_MODEL * D_MODEL;
    int t = threadIdx.x;
#pragma unroll
    for (int p = 0; p < 4; ++p) {
        int row = p * 16 + (t >> 4);
        int c0 = (t & 15) * 4;
        f32v4 v = *(const f32v4*)(W + (size_t)(kb + row) * D_MODEL + nb + c0);
#pragma unroll
        for (int j = 0; j < 4; ++j) ts[row][c0 + j] = bfb(v[j]);
    }
    __syncthreads();
#pragma unroll
    for (int p = 0; p < 2; ++p) {
        int n = p * 32 + (t >> 3);
        int k0 = (t & 7) * 8;
        u16v8 o;
#pragma unroll
        for (int j = 0; j < 8; ++j) o[j] = ts[k0 + j][n];
        *(u16v8*)(out + (size_t)(nb + n) * D_MODEL + kb + k0) = o;
    }
}

// ---------------------------------------------------------------------------
// GEMM: C[8192x1024] = A[8192x1024] * W[1024x1024] + bias
// ---------------------------------------------------------------------------
template<int ABF16, int OMODE>
__global__ __launch_bounds__(256) void gemm_kernel(const void* Aptr, const unsigned short* Wt,
                                                   const float* bias, void* Cptr) {
    __shared__ unsigned short lds_a[128 * 64];   // rows 128B, swizzled
    __shared__ unsigned short lds_b[128 * 64];
    int bid = blockIdx.x;
    int nb = (bid & 7) * 128;
    int mb = (bid >> 3) * 128;
    int tid = threadIdx.x;
    int lane = tid & 63, wid = tid >> 6;
    int l15 = lane & 15, g = lane >> 4;
    int wm = (wid >> 1) * 64, wn = (wid & 1) * 64;

    f32v4 acc[4][4] = {};

    for (int kt = 0; kt < D_MODEL / 64; ++kt) {
        int k0 = kt * 64;
        __syncthreads();
        if constexpr (ABF16) {
            const unsigned short* A = (const unsigned short*)Aptr;
#pragma unroll
            for (int p = 0; p < 4; ++p) {
                int row = p * 32 + (tid >> 3);
                int c0 = (tid & 7) * 8;
                u16v8 v = *(const u16v8*)(A + (size_t)(mb + row) * D_MODEL + k0 + c0);
                *(u16v8*)((char*)lds_a + swz(row * 128 + c0 * 2)) = v;
            }
        } else {
            const float* A = (const float*)Aptr;
#pragma unroll
            for (int p = 0; p < 8; ++p) {
                int row = p * 16 + (tid >> 4);
                int c0 = (tid & 15) * 4;
                f32v4 v = *(const f32v4*)(A + (size_t)(mb + row) * D_MODEL + k0 + c0);
                u16v4 o;
#pragma unroll
                for (int j = 0; j < 4; ++j) o[j] = bfb(v[j]);
                *(u16v4*)((char*)lds_a + swz(row * 128 + c0 * 2)) = o;
            }
        }
#pragma unroll
        for (int p = 0; p < 4; ++p) {
            int row = p * 32 + (tid >> 3);
            int c0 = (tid & 7) * 8;
            u16v8 v = *(const u16v8*)(Wt + (size_t)(nb + row) * D_MODEL + k0 + c0);
            *(u16v8*)((char*)lds_b + swz(row * 128 + c0 * 2)) = v;
        }
        __syncthreads();
#pragma unroll
        for (int kk = 0; kk < 2; ++kk) {
            bf16x8 af[4], bfr[4];
#pragma unroll
            for (int mt = 0; mt < 4; ++mt)
                af[mt] = *(bf16x8*)((char*)lds_a + swz((wm + mt * 16 + l15) * 128 + kk * 64 + g * 16));
#pragma unroll
            for (int nt = 0; nt < 4; ++nt)
                bfr[nt] = *(bf16x8*)((char*)lds_b + swz((wn + nt * 16 + l15) * 128 + kk * 64 + g * 16));
#pragma unroll
            for (int mt = 0; mt < 4; ++mt)
#pragma unroll
                for (int nt = 0; nt < 4; ++nt)
                    acc[mt][nt] = mfma16(af[mt], bfr[nt], acc[mt][nt]);
        }
    }
#pragma unroll
    for (int nt = 0; nt < 4; ++nt) {
        int n = nb + wn + nt * 16 + l15;
        float bv = bias[n];
#pragma unroll
        for (int mt = 0; mt < 4; ++mt) {
#pragma unroll
            for (int r = 0; r < 4; ++r) {
                int m = mb + wm + mt * 16 + 4 * g + r;
                float val = acc[mt][nt][r] + bv;
                if constexpr (OMODE == 0) {
                    unsigned short* out = (unsigned short*)Cptr;
                    int bb = m >> 11, ss = m & 2047, hh = n >> 6, dd = n & 63;
                    out[(((size_t)(bb * N_HEADS + hh)) * SEQ + ss) * DK + dd] = bfb(val);
                } else {
                    float* out = (float*)Cptr;
                    out[(size_t)m * D_MODEL + n] = val;
                }
            }
        }
    }
}

// ---------------------------------------------------------------------------
// Transpose Vh [BH][S][DK] bf16 -> Vt [BH][DK][S] bf16
// ---------------------------------------------------------------------------
__global__ __launch_bounds__(256) void vtrans_kernel(const unsigned short* Vh, unsigned short* Vt) {
    __shared__ unsigned short ts[64][65];
    int bid = blockIdx.x;
    int bh = bid >> 5;
    int s0 = (bid & 31) * 64;
    int t = threadIdx.x;
    const unsigned short* in = Vh + (size_t)bh * SEQ * DK;
    unsigned short* out = Vt + (size_t)bh * DK * SEQ;
#pragma unroll
    for (int p = 0; p < 2; ++p) {
        int srow = p * 32 + (t >> 3);
        int d0 = (t & 7) * 8;
        u16v8 v = *(const u16v8*)(in + (size_t)(s0 + srow) * DK + d0);
#pragma unroll
        for (int j = 0; j < 8; ++j) ts[srow][d0 + j] = v[j];
    }
    __syncthreads();
#pragma unroll
    for (int p = 0; p < 2; ++p) {
        int d = p * 32 + (t >> 3);
        int sc0 = (t & 7) * 8;
        u16v8 o;
#pragma unroll
        for (int j = 0; j < 8; ++j) o[j] = ts[sc0 + j][d];
        *(u16v8*)(out + (size_t)d * SEQ + s0 + sc0) = o;
    }
}

// ---------------------------------------------------------------------------
// Causal flash attention v2.
//  - 4 waves/block, each wave owns 32 q-rows (two 16-row groups) -> 128-row q-tile
//  - paired q-tiles (i, 15-i): every block does exactly 34 KV-tile iterations
//  - double-buffered K/V LDS; global loads issued before compute (T14)
//  - softmax denominator accumulated via ones-column MFMA (no sum butterfly)
// ---------------------------------------------------------------------------
__global__ __launch_bounds__(256, 2) void attn_kernel(const unsigned short* Qh, const unsigned short* Kh,
                                                      const unsigned short* Vt, unsigned short* ctxp) {
    __shared__ unsigned short k_lds[2][64 * 64];
    __shared__ unsigned short v_lds[2][64 * 64];   // [d][key_local]
    __shared__ unsigned short p_lds[4][32 * 64];
    int bid = blockIdx.x;
    int pr = bid & 7;           // pair index 0..7 -> tiles {pr, 15-pr}
    int bh = bid >> 3;
    int bb = bh >> 4, hh = bh & 15;
    int tid = threadIdx.x;
    int wid = tid >> 6, lane = tid & 63;
    int l15 = lane & 15, g = lane >> 4;
    const unsigned short* Qb = Qh + (size_t)bh * SEQ * DK;
    const unsigned short* Kb = Kh + (size_t)bh * SEQ * DK;
    const unsigned short* Vb = Vt + (size_t)bh * DK * SEQ;

    // staging map: sweep p in {0,1}: slot-index si = p*256+tid; row=si>>3, slot=si&7
    int row0 = tid >> 3, slot0 = tid & 7;
    int row1 = (256 + tid) >> 3, slot1 = tid & 7;

    u16v8 kreg[2], vreg[2];
    u16v8 ones_u;
#pragma unroll
    for (int j = 0; j < 8; ++j) ones_u[j] = 0x3F80;   // bf16 1.0
    bf16x8 onesf = __builtin_bit_cast(bf16x8, ones_u);

    for (int half = 0; half < 2; ++half) {
        int qi = half ? (15 - pr) : pr;
        int n_kt = 2 * qi + 2;
        int qw0 = qi * 128 + wid * 32;

        // Q fragments for both row groups, pre-scaled by 1/8
        bf16x8 qf[2][2];
#pragma unroll
        for (int m = 0; m < 2; ++m)
#pragma unroll
            for (int kk = 0; kk < 2; ++kk) {
                u16v8 raw = *(const u16v8*)(Qb + (size_t)(qw0 + m * 16 + l15) * DK + kk * 32 + g * 8);
                u16v8 sc;
#pragma unroll
                for (int j = 0; j < 8; ++j) sc[j] = bfb(bff(raw[j]) * 0.125f);
                qf[m][kk] = __builtin_bit_cast(bf16x8, sc);
            }

        f32v4 acc[2][4] = {};
        f32v4 lac[2] = {};
        float mrun[2][4];
#pragma unroll
        for (int m = 0; m < 2; ++m)
#pragma unroll
            for (int r = 0; r < 4; ++r) mrun[m][r] = -1e30f;

        // prologue: stage tile 0
        kreg[0] = *(const u16v8*)(Kb + (size_t)row0 * DK + slot0 * 8);
        vreg[0] = *(const u16v8*)(Vb + (size_t)row0 * SEQ + slot0 * 8);
        kreg[1] = *(const u16v8*)(Kb + (size_t)row1 * DK + slot1 * 8);
        vreg[1] = *(const u16v8*)(Vb + (size_t)row1 * SEQ + slot1 * 8);
        __syncthreads();   // prior half done reading LDS
        *(u16v8*)((char*)k_lds[0] + swz(row0 * 128 + slot0 * 16)) = kreg[0];
        *(u16v8*)((char*)v_lds[0] + swz(row0 * 128 + slot0 * 16)) = vreg[0];
        *(u16v8*)((char*)k_lds[0] + swz(row1 * 128 + slot1 * 16)) = kreg[1];
        *(u16v8*)((char*)v_lds[0] + swz(row1 * 128 + slot1 * 16)) = vreg[1];
        int cur = 0;
        __syncthreads();

        for (int kt = 0; kt < n_kt; ++kt) {
            bool hasnext = (kt + 1) < n_kt;
            if (hasnext) {   // issue next tile's global loads early
                int kg = (kt + 1) * 64;
                kreg[0] = *(const u16v8*)(Kb + (size_t)(kg + row0) * DK + slot0 * 8);
                vreg[0] = *(const u16v8*)(Vb + (size_t)row0 * SEQ + kg + slot0 * 8);
                kreg[1] = *(const u16v8*)(Kb + (size_t)(kg + row1) * DK + slot1 * 8);
                vreg[1] = *(const u16v8*)(Vb + (size_t)row1 * SEQ + kg + slot1 * 8);
            }
            // QK^T
            f32v4 s[2][4] = {};
#pragma unroll
            for (int kk = 0; kk < 2; ++kk)
#pragma unroll
                for (int c = 0; c < 4; ++c) {
                    bf16x8 kf = *(bf16x8*)((char*)k_lds[cur] + swz((c * 16 + l15) * 128 + kk * 64 + g * 16));
                    s[0][c] = mfma16(qf[0][kk], kf, s[0][c]);
                    s[1][c] = mfma16(qf[1][kk], kf, s[1][c]);
                }
            // mask + online softmax (max only; denom via ones-MFMA)
#pragma unroll
            for (int m = 0; m < 2; ++m) {
                int q0 = qw0 + m * 16;
                if (kt * 64 + 63 > q0) {
#pragma unroll
                    for (int c = 0; c < 4; ++c) {
                        int key = kt * 64 + c * 16 + l15;
#pragma unroll
                        for (int r = 0; r < 4; ++r) {
                            int qq = q0 + 4 * g + r;
                            if (key > qq) s[m][c][r] = -1e30f;
                        }
                    }
                }
#pragma unroll
                for (int r = 0; r < 4; ++r) {
                    float mx = fmaxf(fmaxf(s[m][0][r], s[m][1][r]), fmaxf(s[m][2][r], s[m][3][r]));
#pragma unroll
                    for (int off = 1; off < 16; off <<= 1) mx = fmaxf(mx, __shfl_xor(mx, off));
                    float mn = fmaxf(mrun[m][r], mx);
                    float co = __expf(mrun[m][r] - mn);
                    mrun[m][r] = mn;
#pragma unroll
                    for (int c = 0; c < 4; ++c) s[m][c][r] = __expf(s[m][c][r] - mn);
#pragma unroll
                    for (int c2 = 0; c2 < 4; ++c2) acc[m][c2][r] *= co;
                    lac[m][r] *= co;
                }
            }
            // P -> per-wave LDS (D-layout) -> A-layout fragments
            unsigned short* pw = p_lds[wid];
#pragma unroll
            for (int m = 0; m < 2; ++m)
#pragma unroll
                for (int c = 0; c < 4; ++c)
#pragma unroll
                    for (int r = 0; r < 4; ++r)
                        *(unsigned short*)((char*)pw + swz((m * 16 + 4 * g + r) * 128 + (c * 16 + l15) * 2)) = bfb(s[m][c][r]);
#pragma unroll
            for (int kk = 0; kk < 2; ++kk) {
                bf16x8 pa0 = *(bf16x8*)((char*)pw + swz((l15) * 128 + kk * 64 + g * 16));
                bf16x8 pa1 = *(bf16x8*)((char*)pw + swz((16 + l15) * 128 + kk * 64 + g * 16));
                lac[0] = mfma16(pa0, onesf, lac[0]);
                lac[1] = mfma16(pa1, onesf, lac[1]);
#pragma unroll
                for (int c2 = 0; c2 < 4; ++c2) {
                    bf16x8 vf = *(bf16x8*)((char*)v_lds[cur] + swz((c2 * 16 + l15) * 128 + kk * 64 + g * 16));
                    acc[0][c2] = mfma16(pa0, vf, acc[0][c2]);
                    acc[1][c2] = mfma16(pa1, vf, acc[1][c2]);
                }
            }
            if (hasnext) {   // write next tile into the other buffer
                *(u16v8*)((char*)k_lds[cur ^ 1] + swz(row0 * 128 + slot0 * 16)) = kreg[0];
                *(u16v8*)((char*)v_lds[cur ^ 1] + swz(row0 * 128 + slot0 * 16)) = vreg[0];
                *(u16v8*)((char*)k_lds[cur ^ 1] + swz(row1 * 128 + slot1 * 16)) = kreg[1];
                *(u16v8*)((char*)v_lds[cur ^ 1] + swz(row1 * 128 + slot1 * 16)) = vreg[1];
            }
            __syncthreads();
            cur ^= 1;
        }
        // epilogue: ctx[b][s][h*64 + d] bf16
#pragma unroll
        for (int m = 0; m < 2; ++m)
#pragma unroll
            for (int c2 = 0; c2 < 4; ++c2)
#pragma unroll
                for (int r = 0; r < 4; ++r) {
                    int qq = qw0 + m * 16 + 4 * g + r;
                    float val = acc[m][c2][r] / lac[m][r];
                    ctxp[((size_t)(bb * SEQ + qq)) * D_MODEL + hh * DK + c2 * 16 + l15] = bfb(val);
                }
    }
}

// ---------------------------------------------------------------------------
extern "C" void kernel_launch(void* const* d_in, const int* in_sizes, int n_in,
                              void* d_out, int out_size, void* d_ws, size_t ws_size,
                              hipStream_t stream) {
    const float* q  = (const float*)d_in[0];
    const float* k  = (const float*)d_in[1];
    const float* v  = (const float*)d_in[2];
    const float* wq = (const float*)d_in[4];
    const float* bq = (const float*)d_in[5];
    const float* wk = (const float*)d_in[6];
    const float* bk = (const float*)d_in[7];
    const float* wv = (const float*)d_in[8];
    const float* bv = (const float*)d_in[9];
    const float* wo = (const float*)d_in[10];
    const float* bo = (const float*)d_in[11];

    unsigned short* ws  = (unsigned short*)d_ws;
    const size_t M8 = (size_t)8 * 1024 * 1024;
    unsigned short* Qh  = ws;            // [BH][S][DK]
    unsigned short* Kh  = ws + M8;
    unsigned short* Vt  = ws + 2 * M8;   // [BH][DK][S]
    unsigned short* CTX = ws + 3 * M8;   // Vh temp, then attention output [B][S][D]
    unsigned short* WT  = ws + 4 * M8;   // 4 x [1024][1024] bf16 transposed weights
    const size_t MM = (size_t)D_MODEL * D_MODEL;

    wtrans_kernel<<<dim3(1024), dim3(256), 0, stream>>>(wq, wk, wv, wo, WT);
    gemm_kernel<0, 0><<<dim3(512), dim3(256), 0, stream>>>(q, WT + 0 * MM, bq, Qh);
    gemm_kernel<0, 0><<<dim3(512), dim3(256), 0, stream>>>(k, WT + 1 * MM, bk, Kh);
    gemm_kernel<0, 0><<<dim3(512), dim3(256), 0, stream>>>(v, WT + 2 * MM, bv, CTX); // Vh temp
    vtrans_kernel<<<dim3(2048), dim3(256), 0, stream>>>(CTX, Vt);
    attn_kernel<<<dim3(512), dim3(256), 0, stream>>>(Qh, Kh, Vt, CTX);
    gemm_kernel<1, 1><<<dim3(512), dim3(256), 0, stream>>>(CTX, WT + 3 * MM, bo, (float*)d_out);
}

// Round 3
// 240.294 us; speedup vs baseline: 1.5789x; 1.0877x over previous
//
#include <hip/hip_runtime.h>
#include <hip/hip_bf16.h>

#define D_MODEL 1024
#define N_HEADS 16
#define DK 64
#define SEQ 2048
#define BATCH 4

typedef __attribute__((ext_vector_type(4))) float   f32v4;
typedef __attribute__((ext_vector_type(8))) __bf16  bf16x8;
typedef __attribute__((ext_vector_type(8))) unsigned short u16v8;
typedef __attribute__((ext_vector_type(4))) unsigned short u16v4;

#define QSCALE 0.18033688011112042f   // 0.125 * log2(e)

__device__ __forceinline__ int swz(int byte) {
    return byte ^ (((byte >> 7) & 7) << 4);
}

__device__ __forceinline__ unsigned short bfb(float f) {
    return __builtin_bit_cast(unsigned short, (__bf16)f);
}
__device__ __forceinline__ float bff(unsigned short u) {
    return (float)__builtin_bit_cast(__bf16, u);
}

__device__ __forceinline__ f32v4 mfma16(bf16x8 a, bf16x8 b, f32v4 c) {
    return __builtin_amdgcn_mfma_f32_16x16x32_bf16(a, b, c, 0, 0, 0);
}

#define GL2LDS16(gp, lp) \
    __builtin_amdgcn_global_load_lds((__attribute__((address_space(1))) const void*)(gp), \
                                     (__attribute__((address_space(3))) void*)(lp), 16, 0, 0)

// ---------------------------------------------------------------------------
// fp32 -> bf16 convert (8 elems/thread)
// ---------------------------------------------------------------------------
__global__ __launch_bounds__(256) void cvt_kernel(const float* __restrict__ src,
                                                  unsigned short* __restrict__ dst) {
    size_t e0 = ((size_t)blockIdx.x * 256 + threadIdx.x) * 8;
    f32v4 a = *(const f32v4*)(src + e0);
    f32v4 b = *(const f32v4*)(src + e0 + 4);
    u16v8 o;
#pragma unroll
    for (int j = 0; j < 4; ++j) { o[j] = bfb(a[j]); o[4 + j] = bfb(b[j]); }
    *(u16v8*)(dst + e0) = o;
}

// ---------------------------------------------------------------------------
// Transpose+convert the four 1024x1024 fp32 weight matrices to bf16 Wt[n][k]
// ---------------------------------------------------------------------------
__global__ __launch_bounds__(256) void wtrans_kernel(const float* wq, const float* wk,
                                                     const float* wv, const float* wo,
                                                     unsigned short* wt) {
    __shared__ unsigned short ts[64][65];
    int bid = blockIdx.x;
    int mat = bid >> 8;            // 0..3
    int tile = bid & 255;          // 16x16 tiles of 64x64
    int kb = (tile >> 4) * 64;
    int nb = (tile & 15) * 64;
    const float* W = (mat == 0) ? wq : (mat == 1) ? wk : (mat == 2) ? wv : wo;
    unsigned short* out = wt + (size_t)mat * D_MODEL * D_MODEL;
    int t = threadIdx.x;
#pragma unroll
    for (int p = 0; p < 4; ++p) {
        int row = p * 16 + (t >> 4);
        int c0 = (t & 15) * 4;
        f32v4 v = *(const f32v4*)(W + (size_t)(kb + row) * D_MODEL + nb + c0);
#pragma unroll
        for (int j = 0; j < 4; ++j) ts[row][c0 + j] = bfb(v[j]);
    }
    __syncthreads();
#pragma unroll
    for (int p = 0; p < 2; ++p) {
        int n = p * 32 + (t >> 3);
        int k0 = (t & 7) * 8;
        u16v8 o;
#pragma unroll
        for (int j = 0; j < 8; ++j) o[j] = ts[k0 + j][n];
        *(u16v8*)(out + (size_t)(nb + n) * D_MODEL + kb + k0) = o;
    }
}

// ---------------------------------------------------------------------------
// GEMM (m97 structure): C[8192x1024] = A[8192x1024]bf16 * W^T + bias
// global_load_lds(16B) staging into linear LDS, 2 barriers per K-step.
// OMODE: 0 = bf16 split-head [B,H,S,DK]
//        1 = fp32 linear
//        2 = bf16 Vt [BH][DK][S]  (operand-swapped output-transpose)
// ---------------------------------------------------------------------------
template<int OMODE>
__global__ __launch_bounds__(256) void gemm_kernel(const unsigned short* __restrict__ A,
                                                   const unsigned short* __restrict__ Wt,
                                                   const float* __restrict__ bias, void* Cptr) {
    __shared__ unsigned short lds_a[128 * 64];
    __shared__ unsigned short lds_b[128 * 64];
    int bid0 = blockIdx.x;
    int bid = (bid0 & 7) * 64 + (bid0 >> 3);   // XCD-bijective swizzle (nwg=512)
    int nb = (bid & 7) * 128;
    int mb = (bid >> 3) * 128;
    int tid = threadIdx.x;
    int lane = tid & 63, wid = tid >> 6;
    int l15 = lane & 15, g = lane >> 4;
    int wm = (wid >> 1) * 64, wn = (wid & 1) * 64;

    const int lrow = lane >> 3;          // 0..7 row within 8-row chunk
    const int lcol = (lane & 7) * 8;     // element offset within row

    f32v4 acc[4][4] = {};

    for (int kt = 0; kt < D_MODEL / 64; ++kt) {
        int k0 = kt * 64;
        __syncthreads();
#pragma unroll
        for (int i = 0; i < 4; ++i) {
            int chunk = i * 4 + wid;          // 0..15, wave-uniform
            int row = chunk * 8 + lrow;
            GL2LDS16(A  + (size_t)(mb + row) * D_MODEL + k0 + lcol, (char*)lds_a + chunk * 1024);
            GL2LDS16(Wt + (size_t)(nb + row) * D_MODEL + k0 + lcol, (char*)lds_b + chunk * 1024);
        }
        __syncthreads();
#pragma unroll
        for (int kk = 0; kk < 2; ++kk) {
            bf16x8 fa[4], fb[4];
            if constexpr (OMODE != 2) {
#pragma unroll
                for (int mt = 0; mt < 4; ++mt)
                    fa[mt] = *(bf16x8*)((char*)lds_a + (wm + mt * 16 + l15) * 128 + kk * 64 + g * 16);
#pragma unroll
                for (int nt = 0; nt < 4; ++nt)
                    fb[nt] = *(bf16x8*)((char*)lds_b + (wn + nt * 16 + l15) * 128 + kk * 64 + g * 16);
            } else {
                // swapped: A-operand = W rows (features), B-operand = token rows
#pragma unroll
                for (int x = 0; x < 4; ++x)
                    fa[x] = *(bf16x8*)((char*)lds_b + (wm + x * 16 + l15) * 128 + kk * 64 + g * 16);
#pragma unroll
                for (int y = 0; y < 4; ++y)
                    fb[y] = *(bf16x8*)((char*)lds_a + (wn + y * 16 + l15) * 128 + kk * 64 + g * 16);
            }
#pragma unroll
            for (int i = 0; i < 4; ++i)
#pragma unroll
                for (int j = 0; j < 4; ++j)
                    acc[i][j] = mfma16(fa[i], fb[j], acc[i][j]);
        }
    }

    if constexpr (OMODE != 2) {
#pragma unroll
        for (int nt = 0; nt < 4; ++nt) {
            int n = nb + wn + nt * 16 + l15;
            float bv = bias[n];
#pragma unroll
            for (int mt = 0; mt < 4; ++mt) {
#pragma unroll
                for (int r = 0; r < 4; ++r) {
                    int m = mb + wm + mt * 16 + 4 * g + r;
                    float val = acc[mt][nt][r] + bv;
                    if constexpr (OMODE == 0) {
                        unsigned short* out = (unsigned short*)Cptr;
                        int bb = m >> 11, ss = m & 2047, hh = n >> 6, dd = n & 63;
                        out[(((size_t)(bb * N_HEADS + hh)) * SEQ + ss) * DK + dd] = bfb(val);
                    } else {
                        float* out = (float*)Cptr;
                        out[(size_t)m * D_MODEL + n] = val;
                    }
                }
            }
        }
    } else {
        // acc[x][y]: row = feature n (nb + wm + x*16 + 4g+r), col = token (mb + wn + y*16 + l15)
        unsigned short* out = (unsigned short*)Cptr;
#pragma unroll
        for (int x = 0; x < 4; ++x) {
#pragma unroll
            for (int r = 0; r < 4; ++r) {
                int n = nb + wm + x * 16 + 4 * g + r;
                float bv = bias[n];
                int hh = n >> 6, dd = n & 63;
#pragma unroll
                for (int y = 0; y < 4; ++y) {
                    int tok = mb + wn + y * 16 + l15;
                    int bb = tok >> 11, ss = tok & 2047;
                    float val = acc[x][y][r] + bv;
                    out[((size_t)(bb * N_HEADS + hh) * DK + dd) * SEQ + ss] = bfb(val);
                }
            }
        }
    }
}

// ---------------------------------------------------------------------------
// Causal flash attention (R2 structure + exp2-domain softmax + setprio)
// ---------------------------------------------------------------------------
__global__ __launch_bounds__(256, 2) void attn_kernel(const unsigned short* Qh, const unsigned short* Kh,
                                                      const unsigned short* Vt, unsigned short* ctxp) {
    __shared__ unsigned short k_lds[2][64 * 64];
    __shared__ unsigned short v_lds[2][64 * 64];   // [d][key_local]
    __shared__ unsigned short p_lds[4][32 * 64];
    int bid = blockIdx.x;
    int pr = bid & 7;           // pair index 0..7 -> tiles {pr, 15-pr}
    int bh = bid >> 3;
    int bb = bh >> 4, hh = bh & 15;
    int tid = threadIdx.x;
    int wid = tid >> 6, lane = tid & 63;
    int l15 = lane & 15, g = lane >> 4;
    const unsigned short* Qb = Qh + (size_t)bh * SEQ * DK;
    const unsigned short* Kb = Kh + (size_t)bh * SEQ * DK;
    const unsigned short* Vb = Vt + (size_t)bh * DK * SEQ;

    int row0 = tid >> 3, slot0 = tid & 7;
    int row1 = (256 + tid) >> 3, slot1 = tid & 7;

    u16v8 kreg[2], vreg[2];
    u16v8 ones_u;
#pragma unroll
    for (int j = 0; j < 8; ++j) ones_u[j] = 0x3F80;   // bf16 1.0
    bf16x8 onesf = __builtin_bit_cast(bf16x8, ones_u);

    for (int half = 0; half < 2; ++half) {
        int qi = half ? (15 - pr) : pr;
        int n_kt = 2 * qi + 2;
        int qw0 = qi * 128 + wid * 32;

        // Q fragments, pre-scaled by 0.125*log2(e) (exp2-domain softmax)
        bf16x8 qf[2][2];
#pragma unroll
        for (int m = 0; m < 2; ++m)
#pragma unroll
            for (int kk = 0; kk < 2; ++kk) {
                u16v8 raw = *(const u16v8*)(Qb + (size_t)(qw0 + m * 16 + l15) * DK + kk * 32 + g * 8);
                u16v8 sc;
#pragma unroll
                for (int j = 0; j < 8; ++j) sc[j] = bfb(bff(raw[j]) * QSCALE);
                qf[m][kk] = __builtin_bit_cast(bf16x8, sc);
            }

        f32v4 acc[2][4] = {};
        f32v4 lac[2] = {};
        float mrun[2][4];
#pragma unroll
        for (int m = 0; m < 2; ++m)
#pragma unroll
            for (int r = 0; r < 4; ++r) mrun[m][r] = -1e30f;

        kreg[0] = *(const u16v8*)(Kb + (size_t)row0 * DK + slot0 * 8);
        vreg[0] = *(const u16v8*)(Vb + (size_t)row0 * SEQ + slot0 * 8);
        kreg[1] = *(const u16v8*)(Kb + (size_t)row1 * DK + slot1 * 8);
        vreg[1] = *(const u16v8*)(Vb + (size_t)row1 * SEQ + slot1 * 8);
        __syncthreads();   // prior half done reading LDS
        *(u16v8*)((char*)k_lds[0] + swz(row0 * 128 + slot0 * 16)) = kreg[0];
        *(u16v8*)((char*)v_lds[0] + swz(row0 * 128 + slot0 * 16)) = vreg[0];
        *(u16v8*)((char*)k_lds[0] + swz(row1 * 128 + slot1 * 16)) = kreg[1];
        *(u16v8*)((char*)v_lds[0] + swz(row1 * 128 + slot1 * 16)) = vreg[1];
        int cur = 0;
        __syncthreads();

        for (int kt = 0; kt < n_kt; ++kt) {
            bool hasnext = (kt + 1) < n_kt;
            if (hasnext) {   // issue next tile's global loads early (T14)
                int kg = (kt + 1) * 64;
                kreg[0] = *(const u16v8*)(Kb + (size_t)(kg + row0) * DK + slot0 * 8);
                vreg[0] = *(const u16v8*)(Vb + (size_t)row0 * SEQ + kg + slot0 * 8);
                kreg[1] = *(const u16v8*)(Kb + (size_t)(kg + row1) * DK + slot1 * 8);
                vreg[1] = *(const u16v8*)(Vb + (size_t)row1 * SEQ + kg + slot1 * 8);
            }
            // QK^T
            f32v4 s[2][4] = {};
            __builtin_amdgcn_s_setprio(1);
#pragma unroll
            for (int kk = 0; kk < 2; ++kk)
#pragma unroll
                for (int c = 0; c < 4; ++c) {
                    bf16x8 kf = *(bf16x8*)((char*)k_lds[cur] + swz((c * 16 + l15) * 128 + kk * 64 + g * 16));
                    s[0][c] = mfma16(qf[0][kk], kf, s[0][c]);
                    s[1][c] = mfma16(qf[1][kk], kf, s[1][c]);
                }
            __builtin_amdgcn_s_setprio(0);
            // mask + online softmax (max only; denom via ones-MFMA)
#pragma unroll
            for (int m = 0; m < 2; ++m) {
                int q0 = qw0 + m * 16;
                if (kt * 64 + 63 > q0) {
#pragma unroll
                    for (int c = 0; c < 4; ++c) {
                        int key = kt * 64 + c * 16 + l15;
#pragma unroll
                        for (int r = 0; r < 4; ++r) {
                            int qq = q0 + 4 * g + r;
                            if (key > qq) s[m][c][r] = -1e30f;
                        }
                    }
                }
#pragma unroll
                for (int r = 0; r < 4; ++r) {
                    float mx = fmaxf(fmaxf(s[m][0][r], s[m][1][r]), fmaxf(s[m][2][r], s[m][3][r]));
#pragma unroll
                    for (int off = 1; off < 16; off <<= 1) mx = fmaxf(mx, __shfl_xor(mx, off));
                    float mn = fmaxf(mrun[m][r], mx);
                    float co = __builtin_amdgcn_exp2f(mrun[m][r] - mn);
                    mrun[m][r] = mn;
#pragma unroll
                    for (int c = 0; c < 4; ++c) s[m][c][r] = __builtin_amdgcn_exp2f(s[m][c][r] - mn);
#pragma unroll
                    for (int c2 = 0; c2 < 4; ++c2) acc[m][c2][r] *= co;
                    lac[m][r] *= co;
                }
            }
            // P -> per-wave LDS (D-layout) -> A-layout fragments
            unsigned short* pw = p_lds[wid];
#pragma unroll
            for (int m = 0; m < 2; ++m)
#pragma unroll
                for (int c = 0; c < 4; ++c)
#pragma unroll
                    for (int r = 0; r < 4; ++r)
                        *(unsigned short*)((char*)pw + swz((m * 16 + 4 * g + r) * 128 + (c * 16 + l15) * 2)) = bfb(s[m][c][r]);
            __builtin_amdgcn_s_setprio(1);
#pragma unroll
            for (int kk = 0; kk < 2; ++kk) {
                bf16x8 pa0 = *(bf16x8*)((char*)pw + swz((l15) * 128 + kk * 64 + g * 16));
                bf16x8 pa1 = *(bf16x8*)((char*)pw + swz((16 + l15) * 128 + kk * 64 + g * 16));
                lac[0] = mfma16(pa0, onesf, lac[0]);
                lac[1] = mfma16(pa1, onesf, lac[1]);
#pragma unroll
                for (int c2 = 0; c2 < 4; ++c2) {
                    bf16x8 vf = *(bf16x8*)((char*)v_lds[cur] + swz((c2 * 16 + l15) * 128 + kk * 64 + g * 16));
                    acc[0][c2] = mfma16(pa0, vf, acc[0][c2]);
                    acc[1][c2] = mfma16(pa1, vf, acc[1][c2]);
                }
            }
            __builtin_amdgcn_s_setprio(0);
            if (hasnext) {
                *(u16v8*)((char*)k_lds[cur ^ 1] + swz(row0 * 128 + slot0 * 16)) = kreg[0];
                *(u16v8*)((char*)v_lds[cur ^ 1] + swz(row0 * 128 + slot0 * 16)) = vreg[0];
                *(u16v8*)((char*)k_lds[cur ^ 1] + swz(row1 * 128 + slot1 * 16)) = kreg[1];
                *(u16v8*)((char*)v_lds[cur ^ 1] + swz(row1 * 128 + slot1 * 16)) = vreg[1];
            }
            __syncthreads();
            cur ^= 1;
        }
        // epilogue: ctx[b][s][h*64 + d] bf16
#pragma unroll
        for (int m = 0; m < 2; ++m)
#pragma unroll
            for (int c2 = 0; c2 < 4; ++c2)
#pragma unroll
                for (int r = 0; r < 4; ++r) {
                    int qq = qw0 + m * 16 + 4 * g + r;
                    float val = acc[m][c2][r] / lac[m][r];
                    ctxp[((size_t)(bb * SEQ + qq)) * D_MODEL + hh * DK + c2 * 16 + l15] = bfb(val);
                }
    }
}

// ---------------------------------------------------------------------------
extern "C" void kernel_launch(void* const* d_in, const int* in_sizes, int n_in,
                              void* d_out, int out_size, void* d_ws, size_t ws_size,
                              hipStream_t stream) {
    const float* q  = (const float*)d_in[0];
    const float* k  = (const float*)d_in[1];
    const float* v  = (const float*)d_in[2];
    const float* wq = (const float*)d_in[4];
    const float* bq = (const float*)d_in[5];
    const float* wk = (const float*)d_in[6];
    const float* bk = (const float*)d_in[7];
    const float* wv = (const float*)d_in[8];
    const float* bv = (const float*)d_in[9];
    const float* wo = (const float*)d_in[10];
    const float* bo = (const float*)d_in[11];

    // workspace (ushort elems): Qh 8M | Kh 8M | Vt 8M | X/CTX 8M | WT 4M = 72 MB
    unsigned short* ws  = (unsigned short*)d_ws;
    const size_t M8 = (size_t)8 * 1024 * 1024;
    unsigned short* Qh = ws;
    unsigned short* Kh = ws + M8;
    unsigned short* Vt = ws + 2 * M8;
    unsigned short* X  = ws + 3 * M8;   // bf16 activation staging, later attention CTX
    unsigned short* WT = ws + 4 * M8;
    const size_t MM = (size_t)D_MODEL * D_MODEL;

    wtrans_kernel<<<dim3(1024), dim3(256), 0, stream>>>(wq, wk, wv, wo, WT);
    cvt_kernel<<<dim3(4096), dim3(256), 0, stream>>>(q, X);
    gemm_kernel<0><<<dim3(512), dim3(256), 0, stream>>>(X, WT + 0 * MM, bq, Qh);
    cvt_kernel<<<dim3(4096), dim3(256), 0, stream>>>(k, X);
    gemm_kernel<0><<<dim3(512), dim3(256), 0, stream>>>(X, WT + 1 * MM, bk, Kh);
    cvt_kernel<<<dim3(4096), dim3(256), 0, stream>>>(v, X);
    gemm_kernel<2><<<dim3(512), dim3(256), 0, stream>>>(X, WT + 2 * MM, bv, Vt);
    attn_kernel<<<dim3(512), dim3(256), 0, stream>>>(Qh, Kh, Vt, X);
    gemm_kernel<1><<<dim3(512), dim3(256), 0, stream>>>(X, WT + 3 * MM, bo, (float*)d_out);
}

// Round 4
// 231.178 us; speedup vs baseline: 1.6411x; 1.0394x over previous
//
#include <hip/hip_runtime.h>
#include <hip/hip_bf16.h>

#define D_MODEL 1024
#define N_HEADS 16
#define DK 64
#define SEQ 2048
#define BATCH 4

typedef __attribute__((ext_vector_type(4))) float   f32v4;
typedef __attribute__((ext_vector_type(16))) float  f32v16;
typedef __attribute__((ext_vector_type(8))) __bf16  bf16x8;
typedef __attribute__((ext_vector_type(8))) unsigned short u16v8;
typedef __attribute__((ext_vector_type(4))) unsigned short u16v4;
typedef __attribute__((ext_vector_type(4))) unsigned int   u32v4;

#define QSCALE 0.18033688011112042f   // 0.125 * log2(e)

__device__ __forceinline__ int swz(int byte) {
    return byte ^ (((byte >> 7) & 7) << 4);
}

__device__ __forceinline__ unsigned short bfb(float f) {
    return __builtin_bit_cast(unsigned short, (__bf16)f);
}
__device__ __forceinline__ float bff(unsigned short u) {
    return (float)__builtin_bit_cast(__bf16, u);
}

__device__ __forceinline__ f32v4 mfma16(bf16x8 a, bf16x8 b, f32v4 c) {
    return __builtin_amdgcn_mfma_f32_16x16x32_bf16(a, b, c, 0, 0, 0);
}
__device__ __forceinline__ f32v16 mfma32(bf16x8 a, bf16x8 b, f32v16 c) {
    return __builtin_amdgcn_mfma_f32_32x32x16_bf16(a, b, c, 0, 0, 0);
}

#define GL2LDS16(gp, lp) \
    __builtin_amdgcn_global_load_lds((__attribute__((address_space(1))) const void*)(gp), \
                                     (__attribute__((address_space(3))) void*)(lp), 16, 0, 0)

// ---------------------------------------------------------------------------
// fp32 -> bf16 convert (8 elems/thread)
// ---------------------------------------------------------------------------
__global__ __launch_bounds__(256) void cvt_kernel(const float* __restrict__ src,
                                                  unsigned short* __restrict__ dst) {
    size_t e0 = ((size_t)blockIdx.x * 256 + threadIdx.x) * 8;
    f32v4 a = *(const f32v4*)(src + e0);
    f32v4 b = *(const f32v4*)(src + e0 + 4);
    u16v8 o;
#pragma unroll
    for (int j = 0; j < 4; ++j) { o[j] = bfb(a[j]); o[4 + j] = bfb(b[j]); }
    *(u16v8*)(dst + e0) = o;
}

// ---------------------------------------------------------------------------
// Transpose+convert the four 1024x1024 fp32 weight matrices to bf16 Wt[n][k]
// ---------------------------------------------------------------------------
__global__ __launch_bounds__(256) void wtrans_kernel(const float* wq, const float* wk,
                                                     const float* wv, const float* wo,
                                                     unsigned short* wt) {
    __shared__ unsigned short ts[64][65];
    int bid = blockIdx.x;
    int mat = bid >> 8;            // 0..3
    int tile = bid & 255;          // 16x16 tiles of 64x64
    int kb = (tile >> 4) * 64;
    int nb = (tile & 15) * 64;
    const float* W = (mat == 0) ? wq : (mat == 1) ? wk : (mat == 2) ? wv : wo;
    unsigned short* out = wt + (size_t)mat * D_MODEL * D_MODEL;
    int t = threadIdx.x;
#pragma unroll
    for (int p = 0; p < 4; ++p) {
        int row = p * 16 + (t >> 4);
        int c0 = (t & 15) * 4;
        f32v4 v = *(const f32v4*)(W + (size_t)(kb + row) * D_MODEL + nb + c0);
#pragma unroll
        for (int j = 0; j < 4; ++j) ts[row][c0 + j] = bfb(v[j]);
    }
    __syncthreads();
#pragma unroll
    for (int p = 0; p < 2; ++p) {
        int n = p * 32 + (t >> 3);
        int k0 = (t & 7) * 8;
        u16v8 o;
#pragma unroll
        for (int j = 0; j < 8; ++j) o[j] = ts[k0 + j][n];
        *(u16v8*)(out + (size_t)(nb + n) * D_MODEL + kb + k0) = o;
    }
}

// ---------------------------------------------------------------------------
// GEMM (m97 structure): C[8192x1024] = A[8192x1024]bf16 * W^T + bias
// OMODE: 0 = bf16 split-head [B,H,S,DK], 1 = fp32 linear, 2 = bf16 Vt [BH][DK][S]
// ---------------------------------------------------------------------------
template<int OMODE>
__global__ __launch_bounds__(256) void gemm_kernel(const unsigned short* __restrict__ A,
                                                   const unsigned short* __restrict__ Wt,
                                                   const float* __restrict__ bias, void* Cptr) {
    __shared__ unsigned short lds_a[128 * 64];
    __shared__ unsigned short lds_b[128 * 64];
    int bid0 = blockIdx.x;
    int bid = (bid0 & 7) * 64 + (bid0 >> 3);   // XCD-bijective swizzle (nwg=512)
    int nb = (bid & 7) * 128;
    int mb = (bid >> 3) * 128;
    int tid = threadIdx.x;
    int lane = tid & 63, wid = tid >> 6;
    int l15 = lane & 15, g = lane >> 4;
    int wm = (wid >> 1) * 64, wn = (wid & 1) * 64;

    const int lrow = lane >> 3;
    const int lcol = (lane & 7) * 8;

    f32v4 acc[4][4] = {};

    for (int kt = 0; kt < D_MODEL / 64; ++kt) {
        int k0 = kt * 64;
        __syncthreads();
#pragma unroll
        for (int i = 0; i < 4; ++i) {
            int chunk = i * 4 + wid;
            int row = chunk * 8 + lrow;
            GL2LDS16(A  + (size_t)(mb + row) * D_MODEL + k0 + lcol, (char*)lds_a + chunk * 1024);
            GL2LDS16(Wt + (size_t)(nb + row) * D_MODEL + k0 + lcol, (char*)lds_b + chunk * 1024);
        }
        __syncthreads();
#pragma unroll
        for (int kk = 0; kk < 2; ++kk) {
            bf16x8 fa[4], fb[4];
            if constexpr (OMODE != 2) {
#pragma unroll
                for (int mt = 0; mt < 4; ++mt)
                    fa[mt] = *(bf16x8*)((char*)lds_a + (wm + mt * 16 + l15) * 128 + kk * 64 + g * 16);
#pragma unroll
                for (int nt = 0; nt < 4; ++nt)
                    fb[nt] = *(bf16x8*)((char*)lds_b + (wn + nt * 16 + l15) * 128 + kk * 64 + g * 16);
            } else {
#pragma unroll
                for (int x = 0; x < 4; ++x)
                    fa[x] = *(bf16x8*)((char*)lds_b + (wm + x * 16 + l15) * 128 + kk * 64 + g * 16);
#pragma unroll
                for (int y = 0; y < 4; ++y)
                    fb[y] = *(bf16x8*)((char*)lds_a + (wn + y * 16 + l15) * 128 + kk * 64 + g * 16);
            }
#pragma unroll
            for (int i = 0; i < 4; ++i)
#pragma unroll
                for (int j = 0; j < 4; ++j)
                    acc[i][j] = mfma16(fa[i], fb[j], acc[i][j]);
        }
    }

    if constexpr (OMODE != 2) {
#pragma unroll
        for (int nt = 0; nt < 4; ++nt) {
            int n = nb + wn + nt * 16 + l15;
            float bv = bias[n];
#pragma unroll
            for (int mt = 0; mt < 4; ++mt) {
#pragma unroll
                for (int r = 0; r < 4; ++r) {
                    int m = mb + wm + mt * 16 + 4 * g + r;
                    float val = acc[mt][nt][r] + bv;
                    if constexpr (OMODE == 0) {
                        unsigned short* out = (unsigned short*)Cptr;
                        int bb = m >> 11, ss = m & 2047, hh = n >> 6, dd = n & 63;
                        out[(((size_t)(bb * N_HEADS + hh)) * SEQ + ss) * DK + dd] = bfb(val);
                    } else {
                        float* out = (float*)Cptr;
                        out[(size_t)m * D_MODEL + n] = val;
                    }
                }
            }
        }
    } else {
        unsigned short* out = (unsigned short*)Cptr;
#pragma unroll
        for (int x = 0; x < 4; ++x) {
#pragma unroll
            for (int r = 0; r < 4; ++r) {
                int n = nb + wm + x * 16 + 4 * g + r;
                float bv = bias[n];
                int hh = n >> 6, dd = n & 63;
#pragma unroll
                for (int y = 0; y < 4; ++y) {
                    int tok = mb + wn + y * 16 + l15;
                    int bb = tok >> 11, ss = tok & 2047;
                    float val = acc[x][y][r] + bv;
                    out[((size_t)(bb * N_HEADS + hh) * DK + dd) * SEQ + ss] = bfb(val);
                }
            }
        }
    }
}

// ---------------------------------------------------------------------------
// Causal flash attention v3: swapped-QK in-register softmax, 32x32x16 MFMA.
//  - grid 1024 = 64 bh x 16 q-tiles (128 rows), longest tiles dispatched first
//  - 4 waves/block, wave owns 32 q-rows; lane&31 = q-row (S^T layout)
//  - P kept in registers; D->A layout fix via pack + shfl_xor(32)
//  - defer-max (THR=8): rescale path (16 shfls) rarely fires
//  - LDS 32K (K/V double-buffered) -> 4 blocks/CU
// ---------------------------------------------------------------------------
__global__ __launch_bounds__(256, 4) void attn_kernel(const unsigned short* Qh, const unsigned short* Kh,
                                                      const unsigned short* Vt, unsigned short* ctxp) {
    __shared__ unsigned short k_lds[2][64 * 64];   // [key][d]
    __shared__ unsigned short v_lds[2][64 * 64];   // [d][key]
    int bid = blockIdx.x;
    int tile = 15 - (bid >> 6);     // longest-first
    int bh = bid & 63;
    int bb = bh >> 4, hh = bh & 15;
    int tid = threadIdx.x;
    int wid = tid >> 6, lane = tid & 63;
    int l31 = lane & 31, hi = lane >> 5;
    int qw0 = tile * 128 + wid * 32;
    int qg = qw0 + l31;             // this lane's q-row
    const unsigned short* Qb = Qh + (size_t)bh * SEQ * DK;
    const unsigned short* Kb = Kh + (size_t)bh * SEQ * DK;
    const unsigned short* Vb = Vt + (size_t)bh * DK * SEQ;

    int row0 = tid >> 3, slot0 = tid & 7;
    int row1 = row0 + 32;

    // Q B-fragments (pre-scaled by 0.125*log2e): qf[ks] covers d = ks*16 + hi*8 + j
    bf16x8 qf[4];
#pragma unroll
    for (int ks = 0; ks < 4; ++ks) {
        u16v8 raw = *(const u16v8*)(Qb + (size_t)qg * DK + ks * 16 + hi * 8);
        u16v8 sc;
#pragma unroll
        for (int j = 0; j < 8; ++j) sc[j] = bfb(bff(raw[j]) * QSCALE);
        qf[ks] = __builtin_bit_cast(bf16x8, sc);
    }

    f32v16 o0 = {}, o1 = {};        // O^T-ish: col d = dv*32+l31, rows q via reg map
    float mrun = -1e30f, lsum = 0.f;
    int n_kt = 2 * tile + 2;

    // prologue: stage tile 0
    u16v8 kreg0 = *(const u16v8*)(Kb + (size_t)row0 * DK + slot0 * 8);
    u16v8 vreg0 = *(const u16v8*)(Vb + (size_t)row0 * SEQ + slot0 * 8);
    u16v8 kreg1 = *(const u16v8*)(Kb + (size_t)row1 * DK + slot0 * 8);
    u16v8 vreg1 = *(const u16v8*)(Vb + (size_t)row1 * SEQ + slot0 * 8);
    *(u16v8*)((char*)k_lds[0] + swz(row0 * 128 + slot0 * 16)) = kreg0;
    *(u16v8*)((char*)v_lds[0] + swz(row0 * 128 + slot0 * 16)) = vreg0;
    *(u16v8*)((char*)k_lds[0] + swz(row1 * 128 + slot0 * 16)) = kreg1;
    *(u16v8*)((char*)v_lds[0] + swz(row1 * 128 + slot0 * 16)) = vreg1;
    int cur = 0;
    __syncthreads();

#define PACK2(a, b) (((unsigned)bfb(b) << 16) | (unsigned)bfb(a))
#define PVSTEP(tt, r0, ks)                                                                   \
    {                                                                                        \
        unsigned x0 = PACK2(tt[r0 + 0], tt[r0 + 1]);                                         \
        unsigned x1 = PACK2(tt[r0 + 2], tt[r0 + 3]);                                         \
        unsigned x2 = PACK2(tt[r0 + 4], tt[r0 + 5]);                                         \
        unsigned x3 = PACK2(tt[r0 + 6], tt[r0 + 7]);                                         \
        unsigned sx0 = (unsigned)__shfl_xor((int)x0, 32);                                    \
        unsigned sx1 = (unsigned)__shfl_xor((int)x1, 32);                                    \
        unsigned sx2 = (unsigned)__shfl_xor((int)x2, 32);                                    \
        unsigned sx3 = (unsigned)__shfl_xor((int)x3, 32);                                    \
        u32v4 w;                                                                             \
        w[0] = hi ? sx2 : x0;                                                                \
        w[1] = hi ? sx3 : x1;                                                                \
        w[2] = hi ? x2 : sx0;                                                                \
        w[3] = hi ? x3 : sx1;                                                                \
        bf16x8 paf = __builtin_bit_cast(bf16x8, w);                                          \
        bf16x8 vf0 = *(bf16x8*)((char*)v_lds[cur] + swz(l31 * 128 + ks * 32 + hi * 16));     \
        bf16x8 vf1 = *(bf16x8*)((char*)v_lds[cur] + swz((32 + l31) * 128 + ks * 32 + hi * 16)); \
        o0 = mfma32(paf, vf0, o0);                                                           \
        o1 = mfma32(paf, vf1, o1);                                                           \
    }

    for (int kt = 0; kt < n_kt; ++kt) {
        int ktb = kt * 64;
        bool hasnext = (kt + 1) < n_kt;
        if (hasnext) {   // issue next tile's global loads early (T14)
            int kg = ktb + 64;
            kreg0 = *(const u16v8*)(Kb + (size_t)(kg + row0) * DK + slot0 * 8);
            vreg0 = *(const u16v8*)(Vb + (size_t)row0 * SEQ + kg + slot0 * 8);
            kreg1 = *(const u16v8*)(Kb + (size_t)(kg + row1) * DK + slot0 * 8);
            vreg1 = *(const u16v8*)(Vb + (size_t)row1 * SEQ + kg + slot0 * 8);
        }
        if (ktb <= qw0 + 31) {   // wave has live rows in this tile
            // swapped QK^T: t[kb][r] = S^T, lane q = l31, key = ktb + kb*32 + off(r)
            f32v16 t0 = {}, t1 = {};
            __builtin_amdgcn_s_setprio(1);
#pragma unroll
            for (int ks = 0; ks < 4; ++ks) {
                bf16x8 kf0 = *(bf16x8*)((char*)k_lds[cur] + swz(l31 * 128 + ks * 32 + hi * 16));
                bf16x8 kf1 = *(bf16x8*)((char*)k_lds[cur] + swz((32 + l31) * 128 + ks * 32 + hi * 16));
                t0 = mfma32(kf0, qf[ks], t0);
                t1 = mfma32(kf1, qf[ks], t1);
            }
            __builtin_amdgcn_s_setprio(0);
            // causal mask (diagonal region only)
            if (ktb + 63 > qw0) {
#pragma unroll
                for (int r = 0; r < 16; ++r) {
                    int off = (r & 3) + 8 * (r >> 2) + 4 * hi;
                    if (ktb + off > qg) t0[r] = -1e30f;
                    if (ktb + 32 + off > qg) t1[r] = -1e30f;
                }
            }
            // row max: in-lane tree + cross-half
            float mx = fmaxf(t0[0], t0[1]);
#pragma unroll
            for (int r = 2; r < 16; ++r) mx = fmaxf(mx, t0[r]);
#pragma unroll
            for (int r = 0; r < 16; ++r) mx = fmaxf(mx, t1[r]);
            mx = fmaxf(mx, __shfl_xor(mx, 32));
            // defer-max: rescale only when max grew by > 8 (log2 domain)
            if (__any(mx > mrun + 8.f)) {
                float mn = fmaxf(mrun, mx);
                float co = __builtin_amdgcn_exp2f(mrun - mn);
                mrun = mn;
                lsum *= co;
#pragma unroll
                for (int r = 0; r < 16; ++r) {
                    int off = (r & 3) + 8 * (r >> 2) + 4 * hi;
                    float cr = __shfl(co, off);
                    o0[r] *= cr;
                    o1[r] *= cr;
                }
            }
            // exp2 + partial row-sum (cross-half combined in epilogue)
#pragma unroll
            for (int r = 0; r < 16; ++r) {
                t0[r] = __builtin_amdgcn_exp2f(t0[r] - mrun);
                t1[r] = __builtin_amdgcn_exp2f(t1[r] - mrun);
                lsum += t0[r] + t1[r];
            }
            // PV: P^T(D-layout) -> A-frags in-register, V from v_lds
            __builtin_amdgcn_s_setprio(1);
            PVSTEP(t0, 0, 0)
            PVSTEP(t0, 8, 1)
            PVSTEP(t1, 0, 2)
            PVSTEP(t1, 8, 3)
            __builtin_amdgcn_s_setprio(0);
        }
        if (hasnext) {   // write next tile into the other buffer
            *(u16v8*)((char*)k_lds[cur ^ 1] + swz(row0 * 128 + slot0 * 16)) = kreg0;
            *(u16v8*)((char*)v_lds[cur ^ 1] + swz(row0 * 128 + slot0 * 16)) = vreg0;
            *(u16v8*)((char*)k_lds[cur ^ 1] + swz(row1 * 128 + slot0 * 16)) = kreg1;
            *(u16v8*)((char*)v_lds[cur ^ 1] + swz(row1 * 128 + slot0 * 16)) = vreg1;
        }
        __syncthreads();
        cur ^= 1;
    }

    // epilogue: combine half-row sums, redistribute 1/l, store ctx[b][q][h*64+d]
    float lt = lsum + __shfl_xor(lsum, 32);
    float rinv = 1.f / lt;
#pragma unroll
    for (int r = 0; r < 16; ++r) {
        int off = (r & 3) + 8 * (r >> 2) + 4 * hi;
        float rr = __shfl(rinv, off);
        int qq = qw0 + off;
        size_t base = ((size_t)(bb * SEQ + qq)) * D_MODEL + hh * DK;
        ctxp[base + l31] = bfb(o0[r] * rr);
        ctxp[base + 32 + l31] = bfb(o1[r] * rr);
    }
#undef PVSTEP
#undef PACK2
}

// ---------------------------------------------------------------------------
extern "C" void kernel_launch(void* const* d_in, const int* in_sizes, int n_in,
                              void* d_out, int out_size, void* d_ws, size_t ws_size,
                              hipStream_t stream) {
    const float* q  = (const float*)d_in[0];
    const float* k  = (const float*)d_in[1];
    const float* v  = (const float*)d_in[2];
    const float* wq = (const float*)d_in[4];
    const float* bq = (const float*)d_in[5];
    const float* wk = (const float*)d_in[6];
    const float* bk = (const float*)d_in[7];
    const float* wv = (const float*)d_in[8];
    const float* bv = (const float*)d_in[9];
    const float* wo = (const float*)d_in[10];
    const float* bo = (const float*)d_in[11];

    // workspace (ushort elems): Qh 8M | Kh 8M | Vt 8M | X/CTX 8M | WT 4M = 72 MB
    unsigned short* ws  = (unsigned short*)d_ws;
    const size_t M8 = (size_t)8 * 1024 * 1024;
    unsigned short* Qh = ws;
    unsigned short* Kh = ws + M8;
    unsigned short* Vt = ws + 2 * M8;
    unsigned short* X  = ws + 3 * M8;   // bf16 activation staging, later attention CTX
    unsigned short* WT = ws + 4 * M8;
    const size_t MM = (size_t)D_MODEL * D_MODEL;

    wtrans_kernel<<<dim3(1024), dim3(256), 0, stream>>>(wq, wk, wv, wo, WT);
    cvt_kernel<<<dim3(4096), dim3(256), 0, stream>>>(q, X);
    gemm_kernel<0><<<dim3(512), dim3(256), 0, stream>>>(X, WT + 0 * MM, bq, Qh);
    cvt_kernel<<<dim3(4096), dim3(256), 0, stream>>>(k, X);
    gemm_kernel<0><<<dim3(512), dim3(256), 0, stream>>>(X, WT + 1 * MM, bk, Kh);
    cvt_kernel<<<dim3(4096), dim3(256), 0, stream>>>(v, X);
    gemm_kernel<2><<<dim3(512), dim3(256), 0, stream>>>(X, WT + 2 * MM, bv, Vt);
    attn_kernel<<<dim3(1024), dim3(256), 0, stream>>>(Qh, Kh, Vt, X);
    gemm_kernel<1><<<dim3(512), dim3(256), 0, stream>>>(X, WT + 3 * MM, bo, (float*)d_out);
}